// Round 1
// baseline (296.611 us; speedup 1.0000x reference)
//
#include <hip/hip_runtime.h>

#define TT   2048
#define SS   512
#define NB   16
#define NA   18
#define NROW 2049   // T+1
#define RPB  8      // rows per block in proj kernel
#define NCOL 336    // 288 action + 32 stop + 16 start

// ---------------- kernel A: projections + softmax -> linear-space coefs ----
// coef[row*16+b] = { exp(stop_lp[row,b,0]), exp(stop_lp[row,b,1]),
//                    softmax_start[row,b],  softmax_action[row,b,act[row]] }
__global__ __launch_bounds__(384) void proj_kernel(
    const float* __restrict__ s_i,
    const float* __restrict__ Wa,
    const float* __restrict__ Ws,
    const float* __restrict__ Wst,
    const int*   __restrict__ actions,
    float4*      __restrict__ coef)
{
  __shared__ float lg[RPB][NCOL];
  const int row0 = blockIdx.x * RPB;
  const int t = threadIdx.x;

  if (t < NCOL) {
    const float* W; int ld, c;
    if (t < 288)      { W = Wa;  ld = 288; c = t; }
    else if (t < 320) { W = Ws;  ld = 32;  c = t - 288; }
    else              { W = Wst; ld = 16;  c = t - 320; }
    const float* srow[RPB];
    #pragma unroll
    for (int r = 0; r < RPB; ++r) {
      int rr = row0 + r; if (rr > TT) rr = TT;   // clamp tail (writes guarded below)
      srow[r] = s_i + (size_t)rr * SS;
    }
    float acc[RPB];
    #pragma unroll
    for (int r = 0; r < RPB; ++r) acc[r] = 0.f;
    #pragma unroll 4
    for (int s = 0; s < SS; ++s) {
      float w = W[(size_t)s * ld + c];           // coalesced across lanes
      #pragma unroll
      for (int r = 0; r < RPB; ++r)              // srow[r][s] is wave-uniform -> s_load
        acc[r] = fmaf(w, srow[r][s], acc[r]);
    }
    #pragma unroll
    for (int r = 0; r < RPB; ++r) lg[r][t] = acc[r];
  }
  __syncthreads();

  if (t < RPB * NB) {
    const int r = t >> 4, b = t & 15;
    const int row = row0 + r;
    if (row < NROW) {
      // action softmax over 18, keep prob of chosen action
      float m = -3.4e38f;
      #pragma unroll
      for (int a = 0; a < NA; ++a) m = fmaxf(m, lg[r][b * NA + a]);
      float sum = 0.f;
      #pragma unroll
      for (int a = 0; a < NA; ++a) sum += __expf(lg[r][b * NA + a] - m);
      float aprob = 0.f;
      if (row < TT) {                            // actions has only T entries
        int act = actions[row];
        aprob = __expf(lg[r][b * NA + act] - m) / sum;
      }
      // stop softmax over 2
      float x0 = lg[r][288 + 2 * b], x1 = lg[r][288 + 2 * b + 1];
      float mm = fmaxf(x0, x1);
      float e0 = __expf(x0 - mm), e1 = __expf(x1 - mm);
      float inv = 1.f / (e0 + e1);
      // start softmax over 16
      float ms = -3.4e38f;
      #pragma unroll
      for (int j = 0; j < NB; ++j) ms = fmaxf(ms, lg[r][320 + j]);
      float ssum = 0.f;
      #pragma unroll
      for (int j = 0; j < NB; ++j) ssum += __expf(lg[r][320 + j] - ms);
      float stp = __expf(lg[r][320 + b] - ms) / ssum;

      coef[(size_t)row * NB + b] = make_float4(e0 * inv, e1 * inv, stp, aprob);
    }
  }
}

// ---------------- kernel B: sequential linear-space recurrence -------------
// DPP row_ror rotation all-reduce over the 16-lane row (VALU latency, no LDS).
template <int N>
__device__ __forceinline__ float ror_add(float v) {
  int r = __builtin_amdgcn_mov_dpp(__float_as_int(v), 0x120 + N, 0xF, 0xF, true);
  return v + __int_as_float(r);
}
__device__ __forceinline__ float reduce16(float v) {
  v = ror_add<8>(v); v = ror_add<4>(v); v = ror_add<2>(v); v = ror_add<1>(v);
  return v;  // every lane in the 16-row holds the row sum
}

__global__ __launch_bounds__(64) void scan_kernel(
    const float4* __restrict__ coef, float* __restrict__ out)
{
  const int b = threadIdx.x & 15;
  const float EPEN = 0.60653065971263342f;  // exp(-PEN), PEN = 0.5

  // i = 0: p = softmax(start_0); term_0 = log(sum a_0 * p)
  float4 c0 = coef[b];
  float p = c0.z;
  double tot = (double)__logf(reduce16(c0.w * p));
  long long Ksum = 0;      // sum over steps of Kcum (terms' ln2 parts)
  int Kcum = 0, kpend = 0; // power-of-2 rescale bookkeeping (exact)
  float sc = 1.0f;         // pending scale 2^{-kpend}, folded into next coeffs

  // 8-deep register prefetch pipeline (hides ~500cyc L2/L3 latency)
  float4 buf[8];
  #pragma unroll
  for (int u = 0; u < 8; ++u) buf[u] = coef[(size_t)(1 + u) * NB + b];

  #define STEP(ci)                                                   \
    {                                                                \
      Kcum += kpend;                                                 \
      float s1c = (ci).y * sc;                                       \
      float s0c = (ci).x * sc;                                       \
      float Tv  = reduce16(p * s1c);     /* rearrange mass  */       \
      float ps0 = p * s0c;               /* off critical path */     \
      p = fmaf((ci).z * EPEN, Tv, ps0);                              \
      float U = reduce16((ci).w * p);                                \
      tot += (double)__logf(U);                                      \
      Ksum += (long long)Kcum;                                       \
      int e = ((__float_as_int(Tv) >> 23) & 0xFF) - 126;             \
      e = __builtin_amdgcn_readfirstlane(e); /* uniform across row! */ \
      kpend = e;                                                     \
      sc = __int_as_float((127 - e) << 23);  /* 2^{-e}, exact */     \
    }

  // steps i = 1 .. 2040 in chunks of 8 (prefetch slot u -> row i0+u)
  for (int i0 = 1; i0 <= 2033; i0 += 8) {
    #pragma unroll
    for (int u = 0; u < 8; ++u) {
      float4 ci = buf[u];
      buf[u] = coef[(size_t)(i0 + u + 8) * NB + b];  // max index = 2048
      STEP(ci);
    }
  }
  // tail: i = 2041 .. 2047 (buf[u] holds row 2041+u; buf[7] holds row 2048)
  #pragma unroll
  for (int u = 0; u < 7; ++u) { float4 ci = buf[u]; STEP(ci); }

  // final: + lse_b(stop_lp[T,b,0] + P[T-1,b])
  float Uf = reduce16(buf[7].x * p);
  tot += (double)__logf(Uf);
  Ksum += (long long)Kcum;

  if (threadIdx.x == 0)
    out[0] = (float)(tot + 0.6931471805599453 * (double)Ksum);
  #undef STEP
}

extern "C" void kernel_launch(void* const* d_in, const int* in_sizes, int n_in,
                              void* d_out, int out_size, void* d_ws, size_t ws_size,
                              hipStream_t stream) {
  const float* s_i = (const float*)d_in[0];
  const float* Wa  = (const float*)d_in[1];
  const float* Ws  = (const float*)d_in[2];
  const float* Wst = (const float*)d_in[3];
  const int*   act = (const int*)d_in[4];
  float4* coef = (float4*)d_ws;   // needs 2049*16*16B = 524,544 bytes

  proj_kernel<<<(NROW + RPB - 1) / RPB, 384, 0, stream>>>(s_i, Wa, Ws, Wst, act, coef);
  scan_kernel<<<1, 64, 0, stream>>>(coef, (float*)d_out);
}

// Round 2
// 208.175 us; speedup vs baseline: 1.4248x; 1.4248x over previous
//
#include <hip/hip_runtime.h>

#define TT    2048
#define SS    512
#define NB    16
#define EPEN  0.60653065971263342f   // exp(-0.5)
#define NCHUNK 64
#define CLEN   32                    // NCHUNK*CLEN = 2048 steps (i=1..2048, 2048 virtual)

// ---------------- kernel A: projections + softmax -> linear-space coefs ----
// coef[row*16+b] = { stop0prob, stop1prob, startprob, actprob }
// row 2048 (virtual): { 1, 0, 0, stop0prob }  => A = I, a = stop0
__global__ __launch_bounds__(384) void proj_kernel(
    const float* __restrict__ s_i,
    const float* __restrict__ Wa,
    const float* __restrict__ Ws,
    const float* __restrict__ Wst,
    const int*   __restrict__ actions,
    float4*      __restrict__ coef)
{
  __shared__ float sT[512][12];   // [s][r], stride 12 floats: 16B-aligned rows
  __shared__ float lg[9][344];
  const int tid = threadIdx.x;
  const int row0 = blockIdx.x * 8;
  const int nrows = (blockIdx.x == 0) ? 9 : 8;

  for (int idx = tid; idx < nrows * 512; idx += 384) {
    int r = idx >> 9, s = idx & 511;
    int rr = (r < 8) ? (row0 + r) : TT;
    sT[s][r] = s_i[(size_t)rr * SS + s];
  }
  __syncthreads();

  const bool stop_extra = (blockIdx.x == 0) && (tid >= 288) && (tid < 320);
  if (tid < 336) {
    const float* W; int ld, c;
    if (tid < 288)      { W = Wa;  ld = 288; c = tid; }
    else if (tid < 320) { W = Ws;  ld = 32;  c = tid - 288; }
    else                { W = Wst; ld = 16;  c = tid - 320; }
    float acc[8];
    #pragma unroll
    for (int r = 0; r < 8; ++r) acc[r] = 0.f;
    float acc8 = 0.f;
    #pragma unroll 2
    for (int s = 0; s < 512; ++s) {
      float w = W[(size_t)s * ld + c];
      float4 qa = *(const float4*)&sT[s][0];
      float4 qb = *(const float4*)&sT[s][4];
      acc[0] = fmaf(w, qa.x, acc[0]); acc[1] = fmaf(w, qa.y, acc[1]);
      acc[2] = fmaf(w, qa.z, acc[2]); acc[3] = fmaf(w, qa.w, acc[3]);
      acc[4] = fmaf(w, qb.x, acc[4]); acc[5] = fmaf(w, qb.y, acc[5]);
      acc[6] = fmaf(w, qb.z, acc[6]); acc[7] = fmaf(w, qb.w, acc[7]);
      if (stop_extra) acc8 = fmaf(w, sT[s][8], acc8);
    }
    #pragma unroll
    for (int r = 0; r < 8; ++r) lg[r][tid] = acc[r];
    if (stop_extra) lg[8][tid] = acc8;
  }
  __syncthreads();

  if (tid < 144) {
    const int r = tid >> 4, b = tid & 15;
    if (r < 8) {
      const int row = row0 + r;               // 0..2047
      float m = -3.4e38f;
      #pragma unroll
      for (int a = 0; a < 18; ++a) m = fmaxf(m, lg[r][b * 18 + a]);
      float sum = 0.f;
      #pragma unroll
      for (int a = 0; a < 18; ++a) sum += __expf(lg[r][b * 18 + a] - m);
      int act = actions[row];
      float aprob = __expf(lg[r][b * 18 + act] - m) / sum;

      float x0 = lg[r][288 + 2 * b], x1 = lg[r][288 + 2 * b + 1];
      float mm = fmaxf(x0, x1);
      float e0 = __expf(x0 - mm), e1 = __expf(x1 - mm);
      float inv = 1.f / (e0 + e1);

      float ms = -3.4e38f;
      #pragma unroll
      for (int j = 0; j < 16; ++j) ms = fmaxf(ms, lg[r][320 + j]);
      float ssum = 0.f;
      #pragma unroll
      for (int j = 0; j < 16; ++j) ssum += __expf(lg[r][320 + j] - ms);
      float stp = __expf(lg[r][320 + b] - ms) / ssum;

      coef[(size_t)row * NB + b] = make_float4(e0 * inv, e1 * inv, stp, aprob);
    } else if (blockIdx.x == 0) {
      float x0 = lg[8][288 + 2 * b], x1 = lg[8][288 + 2 * b + 1];
      float mm = fmaxf(x0, x1);
      float e0 = __expf(x0 - mm), e1 = __expf(x1 - mm);
      coef[(size_t)TT * NB + b] = make_float4(1.f, 0.f, 0.f, e0 / (e0 + e1));
    }
  }
}

// ---------------- kernel B: pass1 — chunk transfer matrices + w-vectors ----
// chunk k: steps i = 32k+1 .. 32k+32.  G <- A_i G (lane c owns column c).
// w_i[c] = sum_r a_i[r] * G_i[r][c]  -> Wws[(i-1)*16 + c]
// M_k = G_final -> Mws[k*256 + r*16 + c]
__global__ __launch_bounds__(64) void pass1_kernel(
    const float4* __restrict__ coef,
    float* __restrict__ Wws, float* __restrict__ Mws)
{
  const int chunk = blockIdx.x * 4 + (threadIdx.x >> 4);
  const int c = threadIdx.x & 15;
  const int i0 = chunk * CLEN + 1;

  float G[16];
  #pragma unroll
  for (int r = 0; r < 16; ++r) G[r] = (r == c) ? 1.f : 0.f;

  float4 cfA[16], cfB[16];
  #pragma unroll
  for (int r = 0; r < 16; ++r) cfA[r] = coef[(size_t)i0 * 16 + r];
  #pragma unroll
  for (int r = 0; r < 16; ++r) cfB[r] = coef[(size_t)(i0 + 1) * 16 + r];

#define P1BODY(CUR, NXT, J)                                                  \
  {                                                                          \
    if ((J) + 2 < CLEN) {                                                    \
      _Pragma("unroll")                                                      \
      for (int r = 0; r < 16; ++r)                                           \
        NXT[r] = coef[(size_t)(i0 + (J) + 2) * 16 + r];                      \
    }                                                                        \
    float ta = 0.f, tb = 0.f, tc = 0.f, td = 0.f;                            \
    _Pragma("unroll")                                                        \
    for (int r = 0; r < 4; ++r) {                                            \
      ta = fmaf(CUR[r].y,      G[r],      ta);                               \
      tb = fmaf(CUR[r + 4].y,  G[r + 4],  tb);                               \
      tc = fmaf(CUR[r + 8].y,  G[r + 8],  tc);                               \
      td = fmaf(CUR[r + 12].y, G[r + 12], td);                               \
    }                                                                        \
    float et = EPEN * ((ta + tb) + (tc + td));                               \
    _Pragma("unroll")                                                        \
    for (int r = 0; r < 16; ++r)                                             \
      G[r] = fmaf(CUR[r].x, G[r], CUR[r].z * et);                            \
    float wa = 0.f, wb = 0.f, wc = 0.f, wd = 0.f;                            \
    _Pragma("unroll")                                                        \
    for (int r = 0; r < 4; ++r) {                                            \
      wa = fmaf(CUR[r].w,      G[r],      wa);                               \
      wb = fmaf(CUR[r + 4].w,  G[r + 4],  wb);                               \
      wc = fmaf(CUR[r + 8].w,  G[r + 8],  wc);                               \
      wd = fmaf(CUR[r + 12].w, G[r + 12], wd);                               \
    }                                                                        \
    Wws[(size_t)(chunk * CLEN + (J)) * 16 + c] = (wa + wb) + (wc + wd);      \
  }

  for (int j = 0; j < CLEN; j += 2) {
    P1BODY(cfA, cfB, j);
    P1BODY(cfB, cfA, j + 1);
  }
#undef P1BODY

  #pragma unroll
  for (int r = 0; r < 16; ++r)
    Mws[chunk * 256 + r * 16 + c] = G[r];
}

// ---------------- kernel C: pass2 — sequential chunk walk + term sums -----
template <int N>
__device__ __forceinline__ float ror_add(float v) {
  int r = __builtin_amdgcn_mov_dpp(__float_as_int(v), 0x120 + N, 0xF, 0xF, true);
  return v + __int_as_float(r);
}
__device__ __forceinline__ float reduce16(float v) {
  v = ror_add<8>(v); v = ror_add<4>(v); v = ror_add<2>(v); v = ror_add<1>(v);
  return v;
}

__global__ __launch_bounds__(512) void pass2_kernel(
    const float4* __restrict__ coef,
    const float* __restrict__ Wws, const float* __restrict__ Mws,
    float* __restrict__ out)
{
  __shared__ float lds_p[2][16];
  __shared__ float lds_acc[32];
  const int tid = threadIdx.x;
  const int r = tid >> 4, c = tid & 15;

  // init: p = start probs of row 0; term0
  float4 c0 = coef[c];
  float p = c0.z;
  float U0 = reduce16(c0.w * p);
  float acc = (tid == 0) ? __logf(U0) : 0.f;
  int Ecum = 0;
  long long Ktot = 0;

  // 4-deep prefetch of per-chunk data
  float wbuf[4], mbuf[4];
  #pragma unroll
  for (int q = 0; q < 4; ++q) {
    wbuf[q] = Wws[(size_t)(q * CLEN + r) * 16 + c];
    mbuf[q] = (r < 16) ? Mws[q * 256 + r * 16 + c] : 0.f;
  }

  for (int kb = 0; kb < NCHUNK; kb += 4) {
    #pragma unroll
    for (int q = 0; q < 4; ++q) {
      const int k = kb + q;
      float wc = wbuf[q], mc = mbuf[q];
      if (k + 4 < NCHUNK) {
        wbuf[q] = Wws[(size_t)((k + 4) * CLEN + r) * 16 + c];
        mbuf[q] = (r < 16) ? Mws[(k + 4) * 256 + r * 16 + c] : 0.f;
      }
      // terms for the 32 steps of chunk k (true scale: + Ecum*ln2 each)
      float U = reduce16(wc * p);
      if (c == 0) acc += __logf(U);
      Ktot += 32LL * (long long)Ecum;
      // p' = M_k p  (rows 0..15)
      if (r < 16) {
        float y = reduce16(mc * p);
        if (c == 0) lds_p[k & 1][r] = y;
      }
      __syncthreads();
      float pn = lds_p[k & 1][c];
      float p0 = lds_p[k & 1][0];
      int eb = (__float_as_int(p0) >> 23) & 255;
      Ecum += eb - 127;
      p = pn * __int_as_float((254 - eb) << 23);   // * 2^{-(eb-127)}
    }
  }

  if (c == 0) lds_acc[r] = acc;
  __syncthreads();
  if (tid == 0) {
    double s = 0.0;
    #pragma unroll
    for (int i = 0; i < 32; ++i) s += (double)lds_acc[i];
    out[0] = (float)(s + 0.6931471805599453 * (double)(Ktot / 32 * 32 == Ktot ? Ktot : Ktot));
  }
}

extern "C" void kernel_launch(void* const* d_in, const int* in_sizes, int n_in,
                              void* d_out, int out_size, void* d_ws, size_t ws_size,
                              hipStream_t stream) {
  const float* s_i = (const float*)d_in[0];
  const float* Wa  = (const float*)d_in[1];
  const float* Ws  = (const float*)d_in[2];
  const float* Wst = (const float*)d_in[3];
  const int*   act = (const int*)d_in[4];

  char* ws = (char*)d_ws;
  float4* coef = (float4*)ws;                       //   524,544 B
  float*  Wws  = (float*)(ws + 524544);             // + 131,072 B
  float*  Mws  = (float*)(ws + 524544 + 131072);    // +  65,536 B  (total 721,152)

  proj_kernel <<<256, 384, 0, stream>>>(s_i, Wa, Ws, Wst, act, coef);
  pass1_kernel<<<16,  64,  0, stream>>>(coef, Wws, Mws);
  pass2_kernel<<<1,   512, 0, stream>>>(coef, Wws, Mws, (float*)d_out);
}

// Round 3
// 141.109 us; speedup vs baseline: 2.1020x; 1.4753x over previous
//
#include <hip/hip_runtime.h>

#define TT    2048
#define SS    512
#define NB    16
#define EPEN  0.60653065971263342f   // exp(-0.5)
#define NCHUNK 64
#define CLEN   32

typedef __attribute__((ext_vector_type(4))) float  floatx4;
typedef __attribute__((ext_vector_type(8))) short  bf16x8;

__device__ __forceinline__ ushort f2bf(float x) {   // RNE fp32 -> bf16
  unsigned u = __float_as_uint(x);
  u += 0x7fffu + ((u >> 16) & 1u);
  return (ushort)(u >> 16);
}

// ---------------- kernel 0: W -> transposed bf16  Wt[col][k] ---------------
__global__ __launch_bounds__(256) void prep_kernel(
    const float* __restrict__ Wa, const float* __restrict__ Ws,
    const float* __restrict__ Wst, ushort* __restrict__ Wt)
{
  int idx = blockIdx.x * 256 + threadIdx.x;       // 336*512 = 172032
  if (idx >= 336 * 512) return;
  int col = idx >> 9, k = idx & 511;
  float v;
  if (col < 288)      v = Wa [(size_t)k * 288 + col];
  else if (col < 320) v = Ws [(size_t)k * 32  + (col - 288)];
  else                v = Wst[(size_t)k * 16  + (col - 320)];
  Wt[idx] = f2bf(v);
}

// ---------------- kernel A: MFMA GEMM + softmax -> coef --------------------
// block: 32 rows x 336 cols, 4 waves. wave m-tile = (wave>>1), n-tiles split
// even wave: col-tiles 0..10, odd wave: 11..20.
__global__ __launch_bounds__(256) void proj_kernel(
    const float* __restrict__ s_i,
    const ushort* __restrict__ Wt,
    const int*   __restrict__ actions,
    float4*      __restrict__ coef)
{
  __shared__ ushort At[32 * 40];     // row stride 40 halves (80 B)
  __shared__ ushort Bt[336 * 40];    // col stride 40 halves
  __shared__ float  lg[32][344];

  const int tid  = threadIdx.x;
  const int wave = tid >> 6, lane = tid & 63;
  const int q = lane >> 4, rc = lane & 15;
  const int row0 = blockIdx.x * 32;

  const int mbase  = (wave >> 1) * 16;
  const int ntile0 = (wave & 1) * 11;
  const int ntiles = (wave & 1) ? 10 : 11;

  floatx4 acc[11];
  #pragma unroll
  for (int n = 0; n < 11; ++n) acc[n] = (floatx4)(0.f);

  const int ar  = tid >> 3, akq = tid & 7;        // A staging: row, 4-float chunk
  int agrow = row0 + ar; if (agrow > TT) agrow = TT;
  const float* aptr = s_i + (size_t)agrow * SS + akq * 4;

  for (int kt = 0; kt < 16; ++kt) {
    // ---- stage A tile (fp32 -> bf16) : one float4 per thread
    {
      float4 v = *(const float4*)(aptr + kt * 32);
      ushort4 h; h.x = f2bf(v.x); h.y = f2bf(v.y); h.z = f2bf(v.z); h.w = f2bf(v.w);
      *(ushort4*)(At + ar * 40 + akq * 4) = h;
    }
    // ---- stage B tile: 336 cols x 64 B, 16-B chunks
    #pragma unroll
    for (int i = 0; i < 6; ++i) {
      int idx = i * 256 + tid;
      if (idx < 1344) {
        int col = idx >> 2, ch = idx & 3;
        uint4 v = *(const uint4*)(Wt + (size_t)col * 512 + kt * 32 + ch * 8);
        *(uint4*)(Bt + col * 40 + ch * 8) = v;
      }
    }
    __syncthreads();

    bf16x8 afrag = *(bf16x8*)(At + (mbase + rc) * 40 + q * 8);
    #pragma unroll
    for (int n = 0; n < 11; ++n) {
      if (n < ntiles) {
        int colt = ntile0 + n;
        bf16x8 bfrag = *(bf16x8*)(Bt + (colt * 16 + rc) * 40 + q * 8);
        acc[n] = __builtin_amdgcn_mfma_f32_16x16x32_bf16(afrag, bfrag, acc[n], 0, 0, 0);
      }
    }
    __syncthreads();
  }

  // ---- write logits to LDS (C/D layout: row = q*4+reg, col = rc)
  #pragma unroll
  for (int n = 0; n < 11; ++n) {
    if (n < ntiles) {
      int colt = ntile0 + n;
      #pragma unroll
      for (int reg = 0; reg < 4; ++reg)
        lg[mbase + q * 4 + reg][colt * 16 + rc] = acc[n][reg];
    }
  }
  __syncthreads();

  // ---- softmax epilogue: 32 rows x 16 b, two passes of 256 threads
  #pragma unroll
  for (int h = 0; h < 2; ++h) {
    const int r = h * 16 + (tid >> 4), b = tid & 15;
    const int row = row0 + r;
    if (row < TT) {
      float m = -3.4e38f;
      #pragma unroll
      for (int a = 0; a < 18; ++a) m = fmaxf(m, lg[r][b * 18 + a]);
      float sum = 0.f;
      #pragma unroll
      for (int a = 0; a < 18; ++a) sum += __expf(lg[r][b * 18 + a] - m);
      int act = actions[row];
      float aprob = __expf(lg[r][b * 18 + act] - m) / sum;

      float x0 = lg[r][288 + 2 * b], x1 = lg[r][288 + 2 * b + 1];
      float mm = fmaxf(x0, x1);
      float e0 = __expf(x0 - mm), e1 = __expf(x1 - mm);
      float inv = 1.f / (e0 + e1);

      float ms = -3.4e38f;
      #pragma unroll
      for (int j = 0; j < 16; ++j) ms = fmaxf(ms, lg[r][320 + j]);
      float ssum = 0.f;
      #pragma unroll
      for (int j = 0; j < 16; ++j) ssum += __expf(lg[r][320 + j] - ms);
      float stp = __expf(lg[r][320 + b] - ms) / ssum;

      coef[(size_t)row * NB + b] = make_float4(e0 * inv, e1 * inv, stp, aprob);
    } else if (row == TT) {
      // virtual step 2048: A = I, "action" prob = stop0 prob of row T
      float x0 = lg[r][288 + 2 * b], x1 = lg[r][288 + 2 * b + 1];
      float mm = fmaxf(x0, x1);
      float e0 = __expf(x0 - mm), e1 = __expf(x1 - mm);
      coef[(size_t)TT * NB + b] = make_float4(1.f, 0.f, 0.f, e0 / (e0 + e1));
    }
  }
}

// ---------------- kernel B: pass1 — chunk transfer matrices + w-vectors ----
__global__ __launch_bounds__(64) void pass1_kernel(
    const float4* __restrict__ coef,
    float* __restrict__ Wws, float* __restrict__ Mws)
{
  const int chunk = blockIdx.x * 4 + (threadIdx.x >> 4);
  const int c = threadIdx.x & 15;
  const int i0 = chunk * CLEN + 1;

  float G[16];
  #pragma unroll
  for (int r = 0; r < 16; ++r) G[r] = (r == c) ? 1.f : 0.f;

  float4 cfA[16], cfB[16];
  #pragma unroll
  for (int r = 0; r < 16; ++r) cfA[r] = coef[(size_t)i0 * 16 + r];
  #pragma unroll
  for (int r = 0; r < 16; ++r) cfB[r] = coef[(size_t)(i0 + 1) * 16 + r];

#define P1BODY(CUR, NXT, J)                                                  \
  {                                                                          \
    if ((J) + 2 < CLEN) {                                                    \
      _Pragma("unroll")                                                      \
      for (int r = 0; r < 16; ++r)                                           \
        NXT[r] = coef[(size_t)(i0 + (J) + 2) * 16 + r];                      \
    }                                                                        \
    float ta = 0.f, tb = 0.f, tc = 0.f, td = 0.f;                            \
    _Pragma("unroll")                                                        \
    for (int r = 0; r < 4; ++r) {                                            \
      ta = fmaf(CUR[r].y,      G[r],      ta);                               \
      tb = fmaf(CUR[r + 4].y,  G[r + 4],  tb);                               \
      tc = fmaf(CUR[r + 8].y,  G[r + 8],  tc);                               \
      td = fmaf(CUR[r + 12].y, G[r + 12], td);                               \
    }                                                                        \
    float et = EPEN * ((ta + tb) + (tc + td));                               \
    _Pragma("unroll")                                                        \
    for (int r = 0; r < 16; ++r)                                             \
      G[r] = fmaf(CUR[r].x, G[r], CUR[r].z * et);                            \
    float wa = 0.f, wb = 0.f, wc = 0.f, wd = 0.f;                            \
    _Pragma("unroll")                                                        \
    for (int r = 0; r < 4; ++r) {                                            \
      wa = fmaf(CUR[r].w,      G[r],      wa);                               \
      wb = fmaf(CUR[r + 4].w,  G[r + 4],  wb);                               \
      wc = fmaf(CUR[r + 8].w,  G[r + 8],  wc);                               \
      wd = fmaf(CUR[r + 12].w, G[r + 12], wd);                               \
    }                                                                        \
    Wws[(size_t)(chunk * CLEN + (J)) * 16 + c] = (wa + wb) + (wc + wd);      \
  }

  for (int j = 0; j < CLEN; j += 2) {
    P1BODY(cfA, cfB, j);
    P1BODY(cfB, cfA, j + 1);
  }
#undef P1BODY

  #pragma unroll
  for (int r = 0; r < 16; ++r)
    Mws[chunk * 256 + r * 16 + c] = G[r];
}

// ---------------- kernel C: pass2 — sequential chunk walk + term sums -----
template <int N>
__device__ __forceinline__ float ror_add(float v) {
  int r = __builtin_amdgcn_mov_dpp(__float_as_int(v), 0x120 + N, 0xF, 0xF, true);
  return v + __int_as_float(r);
}
__device__ __forceinline__ float reduce16(float v) {
  v = ror_add<8>(v); v = ror_add<4>(v); v = ror_add<2>(v); v = ror_add<1>(v);
  return v;
}

__global__ __launch_bounds__(512) void pass2_kernel(
    const float4* __restrict__ coef,
    const float* __restrict__ Wws, const float* __restrict__ Mws,
    float* __restrict__ out)
{
  __shared__ float lds_p[2][16];
  __shared__ float lds_acc[32];
  const int tid = threadIdx.x;
  const int r = tid >> 4, c = tid & 15;

  float4 c0 = coef[c];
  float p = c0.z;
  float U0 = reduce16(c0.w * p);
  float acc = (tid == 0) ? __logf(U0) : 0.f;
  int Ecum = 0;
  long long Ktot = 0;

  float wbuf[4], mbuf[4];
  #pragma unroll
  for (int q = 0; q < 4; ++q) {
    wbuf[q] = Wws[(size_t)(q * CLEN + r) * 16 + c];
    mbuf[q] = (r < 16) ? Mws[q * 256 + r * 16 + c] : 0.f;
  }

  for (int kb = 0; kb < NCHUNK; kb += 4) {
    #pragma unroll
    for (int q = 0; q < 4; ++q) {
      const int k = kb + q;
      float wc = wbuf[q], mc = mbuf[q];
      if (k + 4 < NCHUNK) {
        wbuf[q] = Wws[(size_t)((k + 4) * CLEN + r) * 16 + c];
        mbuf[q] = (r < 16) ? Mws[(k + 4) * 256 + r * 16 + c] : 0.f;
      }
      float U = reduce16(wc * p);
      if (c == 0) acc += __logf(U);
      Ktot += 32LL * (long long)Ecum;
      if (r < 16) {
        float y = reduce16(mc * p);
        if (c == 0) lds_p[k & 1][r] = y;
      }
      __syncthreads();
      float pn = lds_p[k & 1][c];
      float p0 = lds_p[k & 1][0];
      int eb = (__float_as_int(p0) >> 23) & 255;
      Ecum += eb - 127;
      p = pn * __int_as_float((254 - eb) << 23);
    }
  }

  if (c == 0) lds_acc[r] = acc;
  __syncthreads();
  if (tid == 0) {
    double s = 0.0;
    #pragma unroll
    for (int i = 0; i < 32; ++i) s += (double)lds_acc[i];
    out[0] = (float)(s + 0.6931471805599453 * (double)Ktot);
  }
}

extern "C" void kernel_launch(void* const* d_in, const int* in_sizes, int n_in,
                              void* d_out, int out_size, void* d_ws, size_t ws_size,
                              hipStream_t stream) {
  const float* s_i = (const float*)d_in[0];
  const float* Wa  = (const float*)d_in[1];
  const float* Ws  = (const float*)d_in[2];
  const float* Wst = (const float*)d_in[3];
  const int*   act = (const int*)d_in[4];

  char* ws = (char*)d_ws;
  float4* coef = (float4*)ws;                        //   524,544 B
  float*  Wws  = (float*)(ws + 524544);              // + 131,072 B
  float*  Mws  = (float*)(ws + 524544 + 131072);     // +  65,536 B
  ushort* Wt   = (ushort*)(ws + 524544 + 131072 + 65536);  // + 344,064 B (total ~1.04 MB)

  prep_kernel <<<672, 256, 0, stream>>>(Wa, Ws, Wst, Wt);
  proj_kernel <<<65,  256, 0, stream>>>(s_i, Wt, act, coef);
  pass1_kernel<<<16,  64,  0, stream>>>(coef, Wws, Mws);
  pass2_kernel<<<1,   512, 0, stream>>>(coef, Wws, Mws, (float*)d_out);
}